// Round 11
// baseline (153.085 us; speedup 1.0000x reference)
//
#include <hip/hip_runtime.h>
#include <hip/hip_bf16.h>

typedef __attribute__((ext_vector_type(8))) __bf16 bf16x8;
typedef __attribute__((ext_vector_type(4))) float f32x4;

#define HBF __hip_bfloat16

// B=2, N=2048, C=768, H=12, D=64
static constexpr float SCALE_C = 0.125f;   // D^-0.5
static constexpr float STEP_C  = 0.1f;
static constexpr float LAMBD_C = 0.5f;

__device__ __forceinline__ int sane_f(float v) {
    float a = fabsf(v);
    return (a <= 1.0e4f && (a >= 1.0e-6f || v == 0.0f)) ? 1 : 0;   // NaN -> 0
}

// ---------------------------------------------------------------------------
// Dtype-detect; canonicalize to bf16 ONLY if inputs are fp32 (else early-exit).
// ---------------------------------------------------------------------------
__global__ __launch_bounds__(256) void convert_all(const void* __restrict__ x,
                                                   const void* __restrict__ wqkv,
                                                   const void* __restrict__ wproj,
                                                   const void* __restrict__ bproj,
                                                   HBF* __restrict__ xb,
                                                   HBF* __restrict__ wqkvb,
                                                   HBF* __restrict__ wprojb,
                                                   HBF* __restrict__ bprojb,
                                                   int* __restrict__ flag) {
    const int t = threadIdx.x, lane = t & 63;
    const unsigned int w = ((const unsigned int*)x)[lane];
    const float f  = __uint_as_float(w);
    const float h0 = __uint_as_float((w & 0xFFFFu) << 16);
    const float h1 = __uint_as_float(w & 0xFFFF0000u);
    int s32 = sane_f(f);
    int s16 = sane_f(h0) + sane_f(h1);
#pragma unroll
    for (int off = 32; off >= 1; off >>= 1) {
        s32 += __shfl_xor(s32, off, 64);
        s16 += __shfl_xor(s16, off, 64);
    }
    const int isf32 = (2 * s32 >= s16) ? 1 : 0;
    if (blockIdx.x == 0 && t == 0) flag[0] = isf32;
    if (!isf32) return;   // bf16 inputs: GEMMs read d_in directly

    constexpr int C0 = (4096 * 768) / 8;
    constexpr int C1 = C0 + (2304 * 768) / 8;
    constexpr int C2 = C1 + (768 * 768) / 8;
    constexpr int C3 = C2 + 768 / 8;

    int i = blockIdx.x * 256 + t;
    const int stride = gridDim.x * 256;
    for (; i < C3; i += stride) {
        const void* src; HBF* dst; int e;
        if (i < C0)      { src = x;     dst = xb;     e = i; }
        else if (i < C1) { src = wqkv;  dst = wqkvb;  e = i - C0; }
        else if (i < C2) { src = wproj; dst = wprojb; e = i - C1; }
        else             { src = bproj; dst = bprojb; e = i - C2; }
        const float4* s = (const float4*)src;
        float4 a = s[2 * e], b = s[2 * e + 1];
        HBF o[8] = {__float2bfloat16(a.x), __float2bfloat16(a.y),
                    __float2bfloat16(a.z), __float2bfloat16(a.w),
                    __float2bfloat16(b.x), __float2bfloat16(b.y),
                    __float2bfloat16(b.z), __float2bfloat16(b.w)};
        ((uint4*)dst)[e] = *(const uint4*)o;
    }
}

// ---------------------------------------------------------------------------
// Double-buffered bf16 GEMM, B^T layout: C[m,n]=sum_k A[m,k]B[n,k] (+bias)
// A/B/bias given as (converted, raw) pairs; selected by runtime flag.
// Tile TM x TN, 256 thr = 4 waves (2x2); wave tile (TM/2)x(TN/2).
// K-loop: barrier -> issue(k+1 into other buf) -> compute(cur buf).
// NOTE: 64x128 is the sweet spot here (dbuf 24KBx2 -> 3+ blocks/CU);
// 128x128 dbuf needs 64KB -> 2 blocks/CU and REGRESSED (R10 post-mortem).
// SPLITQKV (TN=128): fused fp32 L2-norm of Q/K rows; writes Kn/V natural
// [bh][n][64] and QKVt transposed [3][bh][64][2048].
// FINAL: out dtype per runtime flag (1->fp32 scalar, 0->bf16 vector).
// ---------------------------------------------------------------------------
template <int TM, int TN, bool BIAS, bool FINAL, bool SPLITQKV>
__global__ __launch_bounds__(256) void gemm_db(const HBF* __restrict__ Ac,
                                               const void* __restrict__ Ar,
                                               const HBF* __restrict__ Bc,
                                               const void* __restrict__ Br,
                                               const HBF* __restrict__ biasc,
                                               const void* __restrict__ biasr,
                                               void* __restrict__ Cout,
                                               HBF* __restrict__ knat,
                                               HBF* __restrict__ vnat,
                                               HBF* __restrict__ tbuf,
                                               int M, int N, int K,
                                               const int* __restrict__ flagp) {
    constexpr int NI = TM / 32;
    constexpr int NJ = TN / 32;
    constexpr int BUF = (TM + TN) * 64;
    __shared__ HBF smem[2 * BUF];

    const int fl = flagp[0];
    const HBF* A = fl ? Ac : (const HBF*)Ar;
    const HBF* B = fl ? Bc : (const HBF*)Br;
    const HBF* bias = nullptr;
    if (BIAS) bias = fl ? biasc : (const HBF*)biasr;

    const int tid  = threadIdx.x;
    const int wv   = tid >> 6, lane = tid & 63;
    const int m0   = blockIdx.x * TM, n0 = blockIdx.y * TN;
    const int wr = wv >> 1, wc = wv & 1;
    const int l15 = lane & 15, quad = lane >> 4;
    const int srow   = lane >> 3;
    const int schunk = (lane & 7) ^ srow;

    const int NITER = K / 64;

    auto issue = [&](int it) {
        HBF* abase = smem + (it & 1) * BUF;
        HBF* bbase = abase + TM * 64;
        const int k0 = it * 64;
#pragma unroll
        for (int d = 0; d < NI; d++) {
            const int region = d * 4 + wv;
            const int row = region * 8 + srow;
            __builtin_amdgcn_global_load_lds((const void*)(A + (size_t)(m0 + row) * K + k0 + schunk * 8),
                                             (void*)(abase + region * 512), 16, 0, 0);
        }
#pragma unroll
        for (int d = 0; d < NJ; d++) {
            const int region = d * 4 + wv;
            const int row = region * 8 + srow;
            __builtin_amdgcn_global_load_lds((const void*)(B + (size_t)(n0 + row) * K + k0 + schunk * 8),
                                             (void*)(bbase + region * 512), 16, 0, 0);
        }
    };

    f32x4 acc[NI][NJ] = {};

    issue(0);
    for (int it = 0; it < NITER; it++) {
        __syncthreads();
        if (it + 1 < NITER) issue(it + 1);
        const HBF* As = smem + (it & 1) * BUF;
        const HBF* Bs = As + TM * 64;
#pragma unroll
        for (int s = 0; s < 2; s++) {
            bf16x8 af[NI], bfr[NJ];
#pragma unroll
            for (int i = 0; i < NI; i++) {
                const int row = wr * (TM / 2) + i * 16 + l15;
                const int ch = (s * 4 + quad) ^ (row & 7);
                af[i] = *reinterpret_cast<const bf16x8*>(&As[row * 64 + ch * 8]);
            }
#pragma unroll
            for (int j = 0; j < NJ; j++) {
                const int col = wc * (TN / 2) + j * 16 + l15;
                const int ch = (s * 4 + quad) ^ (col & 7);
                bfr[j] = *reinterpret_cast<const bf16x8*>(&Bs[col * 64 + ch * 8]);
            }
#pragma unroll
            for (int i = 0; i < NI; i++)
#pragma unroll
                for (int j = 0; j < NJ; j++)
                    acc[i][j] = __builtin_amdgcn_mfma_f32_16x16x32_bf16(af[i], bfr[j], acc[i][j], 0, 0, 0);
        }
    }
    __syncthreads();

    if (SPLITQKV) {
        // wave tile = (TM/2) rows x 64 cols; cols = exactly one head-slice.
        HBF* wpriv = smem + wv * 4096;   // 8 KB wave-private scratch
        const int colbase = n0 + wc * 64;
        const int tsel = (colbase >= 1536) ? 2 : (colbase >= 768 ? 1 : 0);
        const int h = (colbase - tsel * 768) >> 6;

        if (tsel < 2) {   // fp32 L2-normalize each output row
#pragma unroll
            for (int i = 0; i < NI; i++)
#pragma unroll
                for (int r = 0; r < 4; r++) {
                    float ss = acc[i][0][r] * acc[i][0][r] + acc[i][1][r] * acc[i][1][r]
                             + acc[i][2][r] * acc[i][2][r] + acc[i][3][r] * acc[i][3][r];
#pragma unroll
                    for (int off = 1; off <= 8; off <<= 1) ss += __shfl_xor(ss, off, 64);
                    const float inv = 1.0f / fmaxf(sqrtf(ss), 1e-12f);
#pragma unroll
                    for (int j = 0; j < 4; j++) acc[i][j][r] *= inv;
                }
        }

#pragma unroll
        for (int g = 0; g < NI / 2; g++) {   // 32-row groups
            const int rowstart = m0 + wr * (TM / 2) + g * 32;
            const int b = rowstart >> 11, nloc = rowstart & 2047;
            const size_t bh = (size_t)(b * 12 + h);

            if (tsel != 0) {   // natural store (K normalized, V plain)
                HBF* ep = wpriv;   // [32][72]
#pragma unroll
                for (int ii = 0; ii < 2; ii++) {
                    const int i = g * 2 + ii;
#pragma unroll
                    for (int j = 0; j < 4; j++)
#pragma unroll
                        for (int r = 0; r < 4; r++)
                            ep[(ii * 16 + quad * 4 + r) * 72 + j * 16 + l15] =
                                __float2bfloat16(acc[i][j][r]);
                }
                HBF* dst0 = ((tsel == 2) ? vnat : knat) + (bh * 2048 + nloc) * 64;
#pragma unroll
                for (int itr = 0; itr < 4; itr++) {
                    const int idx = itr * 64 + lane;
                    const int rl = idx >> 3, ch = idx & 7;
                    const uint4 val = *(const uint4*)((const char*)ep + rl * 144 + ch * 16);
                    *(uint4*)((char*)dst0 + rl * 128 + ch * 16) = val;
                }
            }
            {   // transposed store -> QKVt[tsel][bh][d][n]
                HBF* epT = wpriv;  // [64][34] (per-wave DS ops are in-order)
#pragma unroll
                for (int ii = 0; ii < 2; ii++) {
                    const int i = g * 2 + ii;
#pragma unroll
                    for (int j = 0; j < 4; j++)
#pragma unroll
                        for (int r = 0; r < 4; r++)
                            epT[(j * 16 + l15) * 34 + ii * 16 + quad * 4 + r] =
                                __float2bfloat16(acc[i][j][r]);
                }
                HBF* tdst = tbuf + (size_t)tsel * (24 * 64 * 2048) + (bh * 64) * 2048 + nloc;
#pragma unroll
                for (int itr = 0; itr < 4; itr++) {
                    const int idx = itr * 64 + lane;
                    const int d = idx >> 2, c = idx & 3;
                    const uint4 val = *(const uint4*)(epT + d * 34 + c * 8);
                    *(uint4*)(tdst + (size_t)d * 2048 + c * 8) = val;
                }
            }
        }
        return;
    }

    float bvals[NJ];
#pragma unroll
    for (int j = 0; j < NJ; j++) {
        bvals[j] = 0.f;
        if (BIAS) bvals[j] = __bfloat162float(bias[n0 + wc * (TN / 2) + j * 16 + l15]);
    }

    if (FINAL && fl) {   // fp32 output path (only when inputs were fp32)
#pragma unroll
        for (int i = 0; i < NI; i++)
#pragma unroll
            for (int j = 0; j < NJ; j++) {
                const int col = n0 + wc * (TN / 2) + j * 16 + l15;
#pragma unroll
                for (int r = 0; r < 4; r++) {
                    const int row = m0 + wr * (TM / 2) + i * 16 + quad * 4 + r;
                    ((float*)Cout)[(size_t)row * N + col] = acc[i][j][r] + bvals[j];
                }
            }
        return;
    }

    constexpr int RS = (TN / 2) + 8;
    constexpr int CHR = TN / 16;
    constexpr int ITERS = 32 * CHR / 64;
    HBF* ep = smem + wv * (32 * RS);

#pragma unroll
    for (int g = 0; g < NI / 2; g++) {
#pragma unroll
        for (int ii = 0; ii < 2; ii++) {
            const int i = g * 2 + ii;
#pragma unroll
            for (int j = 0; j < NJ; j++)
#pragma unroll
                for (int r = 0; r < 4; r++)
                    ep[(ii * 16 + quad * 4 + r) * RS + j * 16 + l15] =
                        __float2bfloat16(acc[i][j][r] + bvals[j]);
        }
        const int rowstart = m0 + wr * (TM / 2) + g * 32;
#pragma unroll
        for (int itr = 0; itr < ITERS; itr++) {
            const int idx = itr * 64 + lane;
            const int rl = idx / CHR, ch = idx % CHR;
            const uint4 val = *(const uint4*)((const char*)ep + rl * (RS * 2) + ch * 16);
            *(uint4*)((HBF*)Cout + (size_t)(rowstart + rl) * N + n0 + wc * (TN / 2) + ch * 8) = val;
        }
    }
}

// ---------------------------------------------------------------------------
// MFMA Gram partials. Block = (head, 256-n chunk as two 128 sub-chunks).
// ---------------------------------------------------------------------------
__global__ __launch_bounds__(256) void gram_mfma(const HBF* __restrict__ QKVt,
                                                 float* __restrict__ P) {
    __shared__ HBF lds[3 * 8192];   // 48 KB
    const int bh = blockIdx.x, cn = blockIdx.y;
    const int t = threadIdx.x, wv = t >> 6, lane = t & 63;
    const int l15 = lane & 15, quad = lane >> 4;
    constexpr size_t S = (size_t)24 * 64 * 2048;
    const HBF* srcs[3] = {QKVt + S, QKVt, QKVt + 2 * S};   // K, Q, V

    const int rowq = lane >> 4;
    const int cgb  = lane & 15;
    f32x4 aKV[4] = {}, aQV[4] = {}, aQQ[4] = {};
    const int i = wv;

    for (int sub = 0; sub < 2; sub++) {
        if (sub) __syncthreads();
#pragma unroll
        for (int t3 = 0; t3 < 3; t3++) {
            const HBF* base = srcs[t3] + (size_t)bh * 64 * 2048 + cn * 256 + sub * 128;
#pragma unroll
            for (int rg = 0; rg < 4; rg++) {
                const int region = rg * 4 + wv;
                const int row = region * 4 + rowq;
                const int cg = cgb ^ (row & 15);
                __builtin_amdgcn_global_load_lds((const void*)(base + (size_t)row * 2048 + cg * 8),
                                                 (void*)(lds + t3 * 8192 + region * 512), 16, 0, 0);
            }
        }
        __syncthreads();

        const HBF* Kt = lds;
        const HBF* Qt = lds + 8192;
        const HBF* Vt = lds + 16384;
#pragma unroll
        for (int s = 0; s < 4; s++) {
            const int q = (s * 4 + quad) ^ l15;
            const bf16x8 aK = *(const bf16x8*)(Kt + (i * 16 + l15) * 128 + q * 8);
            const bf16x8 aQ = *(const bf16x8*)(Qt + (i * 16 + l15) * 128 + q * 8);
#pragma unroll
            for (int j = 0; j < 4; j++) {
                const bf16x8 bV = *(const bf16x8*)(Vt + (j * 16 + l15) * 128 + q * 8);
                const bf16x8 bQ = *(const bf16x8*)(Qt + (j * 16 + l15) * 128 + q * 8);
                aKV[j] = __builtin_amdgcn_mfma_f32_16x16x32_bf16(aK, bV, aKV[j], 0, 0, 0);
                aQV[j] = __builtin_amdgcn_mfma_f32_16x16x32_bf16(aQ, bV, aQV[j], 0, 0, 0);
                aQQ[j] = __builtin_amdgcn_mfma_f32_16x16x32_bf16(aQ, bQ, aQQ[j], 0, 0, 0);
            }
        }
    }

    float* Pb = P + ((size_t)bh * 8 + cn) * 12288;
#pragma unroll
    for (int j = 0; j < 4; j++)
#pragma unroll
        for (int r = 0; r < 4; r++) {
            const int row = i * 16 + quad * 4 + r, col = j * 16 + l15;
            Pb[row * 64 + col]        = aKV[j][r];
            Pb[4096 + row * 64 + col] = aQV[j][r];
            Pb[8192 + row * 64 + col] = aQQ[j][r];
        }
}

// ---------------------------------------------------------------------------
// FUSED slab-reduce + W combine. One block per head.
// Reduces the 8 P slabs: Mkv -> LDS Kv, Mqq -> LDS Qq, Mqv -> registers.
// Then W = 0.1*s*Mqv - 0.1*s^2*(Mqq@Mkv), stored TRANSPOSED bf16 Wt[d][k].
// ---------------------------------------------------------------------------
__global__ __launch_bounds__(256) void combine_fused(const float* __restrict__ P,
                                                     HBF* __restrict__ Wt) {
    __shared__ float Kv[4096];
    __shared__ float Qq[4096];
    const int bh = blockIdx.x;
    const int t = threadIdx.x;
    const float* Pb = P + (size_t)bh * 8 * 12288;

    float4 mqv[4];
#pragma unroll
    for (int r = 0; r < 12; r++) {
        const int f4 = r * 256 + t;                 // float4 index 0..3071
        float4 s = {0.f, 0.f, 0.f, 0.f};
#pragma unroll
        for (int k = 0; k < 8; k++) {
            const float4 v = ((const float4*)(Pb + (size_t)k * 12288))[f4];
            s.x += v.x; s.y += v.y; s.z += v.z; s.w += v.w;
        }
        const int e = f4 * 4;
        if (e < 4096)        *(float4*)&Kv[e] = s;
        else if (e < 8192)   mqv[r - 4] = s;
        else                 *(float4*)&Qq[e - 8192] = s;
    }
    __syncthreads();

    const int j0 = (t & 15) * 4;
#pragma unroll
    for (int rp = 0; rp < 4; rp++) {
        const int i = rp * 16 + (t >> 4);
        float a0 = 0.f, a1 = 0.f, a2 = 0.f, a3 = 0.f;
#pragma unroll
        for (int k = 0; k < 64; k++) {
            const float q = Qq[i * 64 + k];
            const float4 kv = *(const float4*)&Kv[k * 64 + j0];
            a0 += q * kv.x; a1 += q * kv.y; a2 += q * kv.z; a3 += q * kv.w;
        }
        const float4 mv = mqv[rp];
        HBF* W = Wt + (size_t)bh * 4096;
        W[(j0 + 0) * 64 + i] = __float2bfloat16(STEP_C * (SCALE_C * mv.x - SCALE_C * SCALE_C * a0));
        W[(j0 + 1) * 64 + i] = __float2bfloat16(STEP_C * (SCALE_C * mv.y - SCALE_C * SCALE_C * a1));
        W[(j0 + 2) * 64 + i] = __float2bfloat16(STEP_C * (SCALE_C * mv.z - SCALE_C * SCALE_C * a2));
        W[(j0 + 3) * 64 + i] = __float2bfloat16(STEP_C * (SCALE_C * mv.w - SCALE_C * SCALE_C * a3));
    }
}

// ---------------------------------------------------------------------------
// MFMA epilogue: AO[b,n,h*64+d] = relu(V + (Kn @ W)[n][d] - 0.05), bf16.
// ---------------------------------------------------------------------------
__global__ __launch_bounds__(256) void epilogue_attn(const HBF* __restrict__ Kn,
                                                     const HBF* __restrict__ Vb,
                                                     const HBF* __restrict__ Wt,
                                                     HBF* __restrict__ AO) {
    __shared__ char smem[34816];
    HBF* Ks  = (HBF*)smem;
    HBF* Wts = Ks + 128 * 64;
    float* Ps = (float*)smem;

    const int bh = blockIdx.x, cn = blockIdx.y;
    const int b = bh / 12, h = bh % 12;
    const int t = threadIdx.x, wv = t >> 6, lane = t & 63;
    const int l15 = lane & 15, quad = lane >> 4;
    const size_t kbase = ((size_t)bh * 2048 + cn * 128) * 64;
    const int srow = lane >> 3;
    const int schunk = (lane & 7) ^ srow;
    const int sub = t & 7;

#pragma unroll
    for (int rg = 0; rg < 4; rg++) {
        const int region = rg * 4 + wv;
        const int row = region * 8 + srow;
        __builtin_amdgcn_global_load_lds((const void*)(Kn + kbase + (size_t)row * 64 + schunk * 8),
                                         (void*)(Ks + region * 512), 16, 0, 0);
    }
#pragma unroll
    for (int rg = 0; rg < 2; rg++) {
        const int region = rg * 4 + wv;
        const int row = region * 8 + srow;
        __builtin_amdgcn_global_load_lds((const void*)(Wt + (size_t)bh * 4096 + (size_t)row * 64 + schunk * 8),
                                         (void*)(Wts + region * 512), 16, 0, 0);
    }
    __syncthreads();

    f32x4 acc[2][4] = {};
#pragma unroll
    for (int s = 0; s < 2; s++) {
        const int ch = (s * 4 + quad) ^ (l15 & 7);
        bf16x8 af[2], bfr[4];
#pragma unroll
        for (int i = 0; i < 2; i++) {
            const int row = wv * 32 + i * 16 + l15;
            af[i] = *reinterpret_cast<const bf16x8*>(&Ks[row * 64 + ch * 8]);
        }
#pragma unroll
        for (int j = 0; j < 4; j++) {
            const int d = j * 16 + l15;
            bfr[j] = *reinterpret_cast<const bf16x8*>(&Wts[d * 64 + ch * 8]);
        }
#pragma unroll
        for (int i = 0; i < 2; i++)
#pragma unroll
            for (int j = 0; j < 4; j++)
                acc[i][j] = __builtin_amdgcn_mfma_f32_16x16x32_bf16(af[i], bfr[j], acc[i][j], 0, 0, 0);
    }
    __syncthreads();

    float* Pw = Ps + wv * (32 * 68);
#pragma unroll
    for (int i = 0; i < 2; i++)
#pragma unroll
        for (int j = 0; j < 4; j++)
#pragma unroll
            for (int r = 0; r < 4; r++)
                Pw[(i * 16 + quad * 4 + r) * 68 + j * 16 + l15] = acc[i][j][r];
    __syncthreads();

#pragma unroll
    for (int rr = 0; rr < 4; rr++) {
        const int row = rr * 32 + (t >> 3);
        const float* prow = Ps + (row >> 5) * (32 * 68) + (row & 31) * 68 + sub * 8;
        const float4 p0 = *(const float4*)prow;
        const float4 p1 = *(const float4*)(prow + 4);
        uint4 rv = *(const uint4*)(Vb + kbase + (size_t)row * 64 + sub * 8);
        const HBF* hv = (const HBF*)&rv;
        const float pv[8] = {p0.x, p0.y, p0.z, p0.w, p1.x, p1.y, p1.z, p1.w};
        HBF o[8];
#pragma unroll
        for (int i = 0; i < 8; i++)
            o[i] = __float2bfloat16(fmaxf(__bfloat162float(hv[i]) + pv[i] - (STEP_C * LAMBD_C), 0.f));
        const int n = cn * 128 + row;
        *(uint4*)(AO + ((size_t)b * 2048 + n) * 768 + h * 64 + sub * 8) = *(const uint4*)o;
    }
}

// ---------------------------------------------------------------------------
extern "C" void kernel_launch(void* const* d_in, const int* in_sizes, int n_in,
                              void* d_out, int out_size, void* d_ws, size_t ws_size,
                              hipStream_t stream) {
    char* ws = (char*)d_ws;
    size_t off = 0;
    int*   flag   = (int*)(ws + off);   off += 16;
    HBF*   xb     = (HBF*)(ws + off);   off += (size_t)4096 * 768 * 2;
    HBF*   Wqkvb  = (HBF*)(ws + off);   off += (size_t)2304 * 768 * 2;
    HBF*   Wprojb = (HBF*)(ws + off);   off += (size_t)768 * 768 * 2;
    HBF*   bprojb = (HBF*)(ws + off);   off += 2048;
    HBF*   Kn     = (HBF*)(ws + off);   off += (size_t)24 * 2048 * 64 * 2;
    HBF*   Vb     = (HBF*)(ws + off);   off += (size_t)24 * 2048 * 64 * 2;
    HBF*   QKVt   = (HBF*)(ws + off);   off += (size_t)3 * 24 * 64 * 2048 * 2;
    float* P      = (float*)(ws + off); off += (size_t)24 * 8 * 12288 * 4;
    HBF*   Wt     = (HBF*)(ws + off);   off += (size_t)24 * 4096 * 2;
    HBF*   AO     = (HBF*)(ws + off);   off += (size_t)4096 * 768 * 2;
    // total ~60 MB

    // 0) dtype detect (+ convert only if fp32 inputs)
    convert_all<<<256, 256, 0, stream>>>(d_in[0], d_in[1], d_in[2], d_in[3],
                                         xb, Wqkvb, Wprojb, bprojb, flag);

    // 1) qkv GEMM (double-buffered, 64x128 tiles, 1152 blocks — R9 optimum):
    //    fused L2-norm + head-split natural (Kn, V) + transposed (QKVt)
    gemm_db<64, 128, false, false, true><<<dim3(64, 18), 256, 0, stream>>>(
        xb, d_in[0], Wqkvb, d_in[1], nullptr, nullptr,
        nullptr, Kn, Vb, QKVt, 4096, 2304, 768, flag);

    // 2) MFMA Gram partials (8 slabs)
    gram_mfma<<<dim3(24, 8), 256, 0, stream>>>(QKVt, P);

    // 3) fused slab-reduce + W combine -> transposed bf16 Wt
    combine_fused<<<24, 256, 0, stream>>>(P, Wt);

    // 4) MFMA epilogue: relu(V + Kn@W - 0.05) -> [B,N,C] bf16
    epilogue_attn<<<dim3(24, 16), 256, 0, stream>>>(Kn, Vb, Wt, AO);

    // 5) out = AO @ Wproj^T + bproj (double-buffered, 64x64 tiles, 768 blocks)
    gemm_db<64, 64, true, true, false><<<dim3(64, 12), 256, 0, stream>>>(
        AO, AO, Wprojb, d_in[2], bprojb, d_in[3],
        d_out, nullptr, nullptr, nullptr, 4096, 768, 768, flag);
}

// Round 12
// 140.390 us; speedup vs baseline: 1.0904x; 1.0904x over previous
//
#include <hip/hip_runtime.h>
#include <hip/hip_bf16.h>

typedef __attribute__((ext_vector_type(8))) __bf16 bf16x8;
typedef __attribute__((ext_vector_type(4))) float f32x4;

#define HBF __hip_bfloat16

// B=2, N=2048, C=768, H=12, D=64
static constexpr float SCALE_C = 0.125f;   // D^-0.5
static constexpr float STEP_C  = 0.1f;
static constexpr float LAMBD_C = 0.5f;

__device__ __forceinline__ int sane_f(float v) {
    float a = fabsf(v);
    return (a <= 1.0e4f && (a >= 1.0e-6f || v == 0.0f)) ? 1 : 0;   // NaN -> 0
}

// ---------------------------------------------------------------------------
// Dtype-detect; canonicalize to bf16 ONLY if inputs are fp32 (else early-exit).
// ---------------------------------------------------------------------------
__global__ __launch_bounds__(256) void convert_all(const void* __restrict__ x,
                                                   const void* __restrict__ wqkv,
                                                   const void* __restrict__ wproj,
                                                   const void* __restrict__ bproj,
                                                   HBF* __restrict__ xb,
                                                   HBF* __restrict__ wqkvb,
                                                   HBF* __restrict__ wprojb,
                                                   HBF* __restrict__ bprojb,
                                                   int* __restrict__ flag) {
    const int t = threadIdx.x, lane = t & 63;
    const unsigned int w = ((const unsigned int*)x)[lane];
    const float f  = __uint_as_float(w);
    const float h0 = __uint_as_float((w & 0xFFFFu) << 16);
    const float h1 = __uint_as_float(w & 0xFFFF0000u);
    int s32 = sane_f(f);
    int s16 = sane_f(h0) + sane_f(h1);
#pragma unroll
    for (int off = 32; off >= 1; off >>= 1) {
        s32 += __shfl_xor(s32, off, 64);
        s16 += __shfl_xor(s16, off, 64);
    }
    const int isf32 = (2 * s32 >= s16) ? 1 : 0;
    if (blockIdx.x == 0 && t == 0) flag[0] = isf32;
    if (!isf32) return;   // bf16 inputs: GEMMs read d_in directly

    constexpr int C0 = (4096 * 768) / 8;
    constexpr int C1 = C0 + (2304 * 768) / 8;
    constexpr int C2 = C1 + (768 * 768) / 8;
    constexpr int C3 = C2 + 768 / 8;

    int i = blockIdx.x * 256 + t;
    const int stride = gridDim.x * 256;
    for (; i < C3; i += stride) {
        const void* src; HBF* dst; int e;
        if (i < C0)      { src = x;     dst = xb;     e = i; }
        else if (i < C1) { src = wqkv;  dst = wqkvb;  e = i - C0; }
        else if (i < C2) { src = wproj; dst = wprojb; e = i - C1; }
        else             { src = bproj; dst = bprojb; e = i - C2; }
        const float4* s = (const float4*)src;
        float4 a = s[2 * e], b = s[2 * e + 1];
        HBF o[8] = {__float2bfloat16(a.x), __float2bfloat16(a.y),
                    __float2bfloat16(a.z), __float2bfloat16(a.w),
                    __float2bfloat16(b.x), __float2bfloat16(b.y),
                    __float2bfloat16(b.z), __float2bfloat16(b.w)};
        ((uint4*)dst)[e] = *(const uint4*)o;
    }
}

// ---------------------------------------------------------------------------
// Double-buffered bf16 GEMM, B^T layout: C[m,n]=sum_k A[m,k]B[n,k] (+bias)
// A/B/bias given as (converted, raw) pairs; selected by runtime flag.
// Tile TM x TN, 256 thr = 4 waves (2x2); wave tile (TM/2)x(TN/2).
// K-loop: barrier -> issue(k+1 into other buf) -> compute(cur buf).
// NOTE: 64x128 is the sweet spot (dbuf 24KBx2 -> 3+ blocks/CU); 128x128 dbuf
// (64KB, 2 blocks/CU) REGRESSED [R10]; fused 24-block combine REGRESSED [R11].
// SPLITQKV (TN=128): fused fp32 L2-norm of Q/K rows; writes Kn/V natural
// [bh][n][64] and QKVt transposed [3][bh][64][2048].
// FINAL: out dtype per runtime flag (1->fp32 scalar, 0->bf16 vector).
// ---------------------------------------------------------------------------
template <int TM, int TN, bool BIAS, bool FINAL, bool SPLITQKV>
__global__ __launch_bounds__(256) void gemm_db(const HBF* __restrict__ Ac,
                                               const void* __restrict__ Ar,
                                               const HBF* __restrict__ Bc,
                                               const void* __restrict__ Br,
                                               const HBF* __restrict__ biasc,
                                               const void* __restrict__ biasr,
                                               void* __restrict__ Cout,
                                               HBF* __restrict__ knat,
                                               HBF* __restrict__ vnat,
                                               HBF* __restrict__ tbuf,
                                               int M, int N, int K,
                                               const int* __restrict__ flagp) {
    constexpr int NI = TM / 32;
    constexpr int NJ = TN / 32;
    constexpr int BUF = (TM + TN) * 64;
    __shared__ HBF smem[2 * BUF];

    const int fl = flagp[0];
    const HBF* A = fl ? Ac : (const HBF*)Ar;
    const HBF* B = fl ? Bc : (const HBF*)Br;
    const HBF* bias = nullptr;
    if (BIAS) bias = fl ? biasc : (const HBF*)biasr;

    const int tid  = threadIdx.x;
    const int wv   = tid >> 6, lane = tid & 63;
    const int m0   = blockIdx.x * TM, n0 = blockIdx.y * TN;
    const int wr = wv >> 1, wc = wv & 1;
    const int l15 = lane & 15, quad = lane >> 4;
    const int srow   = lane >> 3;
    const int schunk = (lane & 7) ^ srow;

    const int NITER = K / 64;

    auto issue = [&](int it) {
        HBF* abase = smem + (it & 1) * BUF;
        HBF* bbase = abase + TM * 64;
        const int k0 = it * 64;
#pragma unroll
        for (int d = 0; d < NI; d++) {
            const int region = d * 4 + wv;
            const int row = region * 8 + srow;
            __builtin_amdgcn_global_load_lds((const void*)(A + (size_t)(m0 + row) * K + k0 + schunk * 8),
                                             (void*)(abase + region * 512), 16, 0, 0);
        }
#pragma unroll
        for (int d = 0; d < NJ; d++) {
            const int region = d * 4 + wv;
            const int row = region * 8 + srow;
            __builtin_amdgcn_global_load_lds((const void*)(B + (size_t)(n0 + row) * K + k0 + schunk * 8),
                                             (void*)(bbase + region * 512), 16, 0, 0);
        }
    };

    f32x4 acc[NI][NJ] = {};

    issue(0);
    for (int it = 0; it < NITER; it++) {
        __syncthreads();
        if (it + 1 < NITER) issue(it + 1);
        const HBF* As = smem + (it & 1) * BUF;
        const HBF* Bs = As + TM * 64;
#pragma unroll
        for (int s = 0; s < 2; s++) {
            bf16x8 af[NI], bfr[NJ];
#pragma unroll
            for (int i = 0; i < NI; i++) {
                const int row = wr * (TM / 2) + i * 16 + l15;
                const int ch = (s * 4 + quad) ^ (row & 7);
                af[i] = *reinterpret_cast<const bf16x8*>(&As[row * 64 + ch * 8]);
            }
#pragma unroll
            for (int j = 0; j < NJ; j++) {
                const int col = wc * (TN / 2) + j * 16 + l15;
                const int ch = (s * 4 + quad) ^ (col & 7);
                bfr[j] = *reinterpret_cast<const bf16x8*>(&Bs[col * 64 + ch * 8]);
            }
#pragma unroll
            for (int i = 0; i < NI; i++)
#pragma unroll
                for (int j = 0; j < NJ; j++)
                    acc[i][j] = __builtin_amdgcn_mfma_f32_16x16x32_bf16(af[i], bfr[j], acc[i][j], 0, 0, 0);
        }
    }
    __syncthreads();

    if (SPLITQKV) {
        // wave tile = (TM/2) rows x 64 cols; cols = exactly one head-slice.
        HBF* wpriv = smem + wv * 4096;   // 8 KB wave-private scratch
        const int colbase = n0 + wc * 64;
        const int tsel = (colbase >= 1536) ? 2 : (colbase >= 768 ? 1 : 0);
        const int h = (colbase - tsel * 768) >> 6;

        if (tsel < 2) {   // fp32 L2-normalize each output row
#pragma unroll
            for (int i = 0; i < NI; i++)
#pragma unroll
                for (int r = 0; r < 4; r++) {
                    float ss = acc[i][0][r] * acc[i][0][r] + acc[i][1][r] * acc[i][1][r]
                             + acc[i][2][r] * acc[i][2][r] + acc[i][3][r] * acc[i][3][r];
#pragma unroll
                    for (int off = 1; off <= 8; off <<= 1) ss += __shfl_xor(ss, off, 64);
                    const float inv = 1.0f / fmaxf(sqrtf(ss), 1e-12f);
#pragma unroll
                    for (int j = 0; j < 4; j++) acc[i][j][r] *= inv;
                }
        }

#pragma unroll
        for (int g = 0; g < NI / 2; g++) {   // 32-row groups
            const int rowstart = m0 + wr * (TM / 2) + g * 32;
            const int b = rowstart >> 11, nloc = rowstart & 2047;
            const size_t bh = (size_t)(b * 12 + h);

            if (tsel != 0) {   // natural store (K normalized, V plain)
                HBF* ep = wpriv;   // [32][72]
#pragma unroll
                for (int ii = 0; ii < 2; ii++) {
                    const int i = g * 2 + ii;
#pragma unroll
                    for (int j = 0; j < 4; j++)
#pragma unroll
                        for (int r = 0; r < 4; r++)
                            ep[(ii * 16 + quad * 4 + r) * 72 + j * 16 + l15] =
                                __float2bfloat16(acc[i][j][r]);
                }
                HBF* dst0 = ((tsel == 2) ? vnat : knat) + (bh * 2048 + nloc) * 64;
#pragma unroll
                for (int itr = 0; itr < 4; itr++) {
                    const int idx = itr * 64 + lane;
                    const int rl = idx >> 3, ch = idx & 7;
                    const uint4 val = *(const uint4*)((const char*)ep + rl * 144 + ch * 16);
                    *(uint4*)((char*)dst0 + rl * 128 + ch * 16) = val;
                }
            }
            {   // transposed store -> QKVt[tsel][bh][d][n]
                HBF* epT = wpriv;  // [64][34] (per-wave DS ops are in-order)
#pragma unroll
                for (int ii = 0; ii < 2; ii++) {
                    const int i = g * 2 + ii;
#pragma unroll
                    for (int j = 0; j < 4; j++)
#pragma unroll
                        for (int r = 0; r < 4; r++)
                            epT[(j * 16 + l15) * 34 + ii * 16 + quad * 4 + r] =
                                __float2bfloat16(acc[i][j][r]);
                }
                HBF* tdst = tbuf + (size_t)tsel * (24 * 64 * 2048) + (bh * 64) * 2048 + nloc;
#pragma unroll
                for (int itr = 0; itr < 4; itr++) {
                    const int idx = itr * 64 + lane;
                    const int d = idx >> 2, c = idx & 3;
                    const uint4 val = *(const uint4*)(epT + d * 34 + c * 8);
                    *(uint4*)(tdst + (size_t)d * 2048 + c * 8) = val;
                }
            }
        }
        return;
    }

    float bvals[NJ];
#pragma unroll
    for (int j = 0; j < NJ; j++) {
        bvals[j] = 0.f;
        if (BIAS) bvals[j] = __bfloat162float(bias[n0 + wc * (TN / 2) + j * 16 + l15]);
    }

    if (FINAL && fl) {   // fp32 output path (only when inputs were fp32)
#pragma unroll
        for (int i = 0; i < NI; i++)
#pragma unroll
            for (int j = 0; j < NJ; j++) {
                const int col = n0 + wc * (TN / 2) + j * 16 + l15;
#pragma unroll
                for (int r = 0; r < 4; r++) {
                    const int row = m0 + wr * (TM / 2) + i * 16 + quad * 4 + r;
                    ((float*)Cout)[(size_t)row * N + col] = acc[i][j][r] + bvals[j];
                }
            }
        return;
    }

    constexpr int RS = (TN / 2) + 8;
    constexpr int CHR = TN / 16;
    constexpr int ITERS = 32 * CHR / 64;
    HBF* ep = smem + wv * (32 * RS);

#pragma unroll
    for (int g = 0; g < NI / 2; g++) {
#pragma unroll
        for (int ii = 0; ii < 2; ii++) {
            const int i = g * 2 + ii;
#pragma unroll
            for (int j = 0; j < NJ; j++)
#pragma unroll
                for (int r = 0; r < 4; r++)
                    ep[(ii * 16 + quad * 4 + r) * RS + j * 16 + l15] =
                        __float2bfloat16(acc[i][j][r] + bvals[j]);
        }
        const int rowstart = m0 + wr * (TM / 2) + g * 32;
#pragma unroll
        for (int itr = 0; itr < ITERS; itr++) {
            const int idx = itr * 64 + lane;
            const int rl = idx / CHR, ch = idx % CHR;
            const uint4 val = *(const uint4*)((const char*)ep + rl * (RS * 2) + ch * 16);
            *(uint4*)((HBF*)Cout + (size_t)(rowstart + rl) * N + n0 + wc * (TN / 2) + ch * 8) = val;
        }
    }
}

// ---------------------------------------------------------------------------
// MFMA Gram partials. Block = (head, 256-n chunk as two 128 sub-chunks).
// ---------------------------------------------------------------------------
__global__ __launch_bounds__(256) void gram_mfma(const HBF* __restrict__ QKVt,
                                                 float* __restrict__ P) {
    __shared__ HBF lds[3 * 8192];   // 48 KB
    const int bh = blockIdx.x, cn = blockIdx.y;
    const int t = threadIdx.x, wv = t >> 6, lane = t & 63;
    const int l15 = lane & 15, quad = lane >> 4;
    constexpr size_t S = (size_t)24 * 64 * 2048;
    const HBF* srcs[3] = {QKVt + S, QKVt, QKVt + 2 * S};   // K, Q, V

    const int rowq = lane >> 4;
    const int cgb  = lane & 15;
    f32x4 aKV[4] = {}, aQV[4] = {}, aQQ[4] = {};
    const int i = wv;

    for (int sub = 0; sub < 2; sub++) {
        if (sub) __syncthreads();
#pragma unroll
        for (int t3 = 0; t3 < 3; t3++) {
            const HBF* base = srcs[t3] + (size_t)bh * 64 * 2048 + cn * 256 + sub * 128;
#pragma unroll
            for (int rg = 0; rg < 4; rg++) {
                const int region = rg * 4 + wv;
                const int row = region * 4 + rowq;
                const int cg = cgb ^ (row & 15);
                __builtin_amdgcn_global_load_lds((const void*)(base + (size_t)row * 2048 + cg * 8),
                                                 (void*)(lds + t3 * 8192 + region * 512), 16, 0, 0);
            }
        }
        __syncthreads();

        const HBF* Kt = lds;
        const HBF* Qt = lds + 8192;
        const HBF* Vt = lds + 16384;
#pragma unroll
        for (int s = 0; s < 4; s++) {
            const int q = (s * 4 + quad) ^ l15;
            const bf16x8 aK = *(const bf16x8*)(Kt + (i * 16 + l15) * 128 + q * 8);
            const bf16x8 aQ = *(const bf16x8*)(Qt + (i * 16 + l15) * 128 + q * 8);
#pragma unroll
            for (int j = 0; j < 4; j++) {
                const bf16x8 bV = *(const bf16x8*)(Vt + (j * 16 + l15) * 128 + q * 8);
                const bf16x8 bQ = *(const bf16x8*)(Qt + (j * 16 + l15) * 128 + q * 8);
                aKV[j] = __builtin_amdgcn_mfma_f32_16x16x32_bf16(aK, bV, aKV[j], 0, 0, 0);
                aQV[j] = __builtin_amdgcn_mfma_f32_16x16x32_bf16(aQ, bV, aQV[j], 0, 0, 0);
                aQQ[j] = __builtin_amdgcn_mfma_f32_16x16x32_bf16(aQ, bQ, aQQ[j], 0, 0, 0);
            }
        }
    }

    float* Pb = P + ((size_t)bh * 8 + cn) * 12288;
#pragma unroll
    for (int j = 0; j < 4; j++)
#pragma unroll
        for (int r = 0; r < 4; r++) {
            const int row = i * 16 + quad * 4 + r, col = j * 16 + l15;
            Pb[row * 64 + col]        = aKV[j][r];
            Pb[4096 + row * 64 + col] = aQV[j][r];
            Pb[8192 + row * 64 + col] = aQQ[j][r];
        }
}

// Sum the 8 slabs per head (1152 blocks: full-BW reduce — do NOT fuse into
// the 24-block combine; that serialized the 9.4 MB read and cost 13 µs [R11]).
__global__ __launch_bounds__(256) void gram_reduce(const float* __restrict__ P,
                                                   float* __restrict__ M) {
    const int o = blockIdx.x * 256 + threadIdx.x;
    const int head = o / 12288, e = o % 12288;
    const float* Pb = P + (size_t)head * 8 * 12288 + e;
    float s = 0.f;
#pragma unroll
    for (int k = 0; k < 8; k++) s += Pb[(size_t)k * 12288];
    M[o] = s;
}

// ---------------------------------------------------------------------------
// W = 0.1*s*Mqv - 0.1*s^2 * (Mqq @ Mkv); emit TRANSPOSED bf16 Wt[d][k].
// ---------------------------------------------------------------------------
__global__ __launch_bounds__(256) void combine_w(const float* __restrict__ M,
                                                 HBF* __restrict__ Wt) {
    const int bh = blockIdx.x;
    const int by = blockIdx.y;
    const int t = threadIdx.x;
    __shared__ float Kv[4096];
    __shared__ float Qq8[512];
    const float* Mb = M + (size_t)bh * 12288;
#pragma unroll
    for (int r = 0; r < 16; r++) Kv[t + 256 * r] = Mb[t + 256 * r];
#pragma unroll
    for (int r = 0; r < 2; r++)  Qq8[t + 256 * r] = Mb[8192 + by * 512 + t + 256 * r];
    __syncthreads();

    const int il = t >> 5;
    const int j0 = (t & 31) * 2;
    float s0 = 0.f, s1 = 0.f;
#pragma unroll
    for (int k = 0; k < 64; k++) {
        const float q = Qq8[il * 64 + k];
        const float2 kv = *(const float2*)&Kv[k * 64 + j0];
        s0 += q * kv.x;
        s1 += q * kv.y;
    }
    const int i = by * 8 + il;
    const float w0 = STEP_C * (SCALE_C * Mb[4096 + i * 64 + j0]     - SCALE_C * SCALE_C * s0);
    const float w1 = STEP_C * (SCALE_C * Mb[4096 + i * 64 + j0 + 1] - SCALE_C * SCALE_C * s1);
    Wt[(size_t)bh * 4096 + j0 * 64 + i]       = __float2bfloat16(w0);
    Wt[(size_t)bh * 4096 + (j0 + 1) * 64 + i] = __float2bfloat16(w1);
}

// ---------------------------------------------------------------------------
// MFMA epilogue: AO[b,n,h*64+d] = relu(V + (Kn @ W)[n][d] - 0.05), bf16.
// ---------------------------------------------------------------------------
__global__ __launch_bounds__(256) void epilogue_attn(const HBF* __restrict__ Kn,
                                                     const HBF* __restrict__ Vb,
                                                     const HBF* __restrict__ Wt,
                                                     HBF* __restrict__ AO) {
    __shared__ char smem[34816];
    HBF* Ks  = (HBF*)smem;
    HBF* Wts = Ks + 128 * 64;
    float* Ps = (float*)smem;

    const int bh = blockIdx.x, cn = blockIdx.y;
    const int b = bh / 12, h = bh % 12;
    const int t = threadIdx.x, wv = t >> 6, lane = t & 63;
    const int l15 = lane & 15, quad = lane >> 4;
    const size_t kbase = ((size_t)bh * 2048 + cn * 128) * 64;
    const int srow = lane >> 3;
    const int schunk = (lane & 7) ^ srow;
    const int sub = t & 7;

#pragma unroll
    for (int rg = 0; rg < 4; rg++) {
        const int region = rg * 4 + wv;
        const int row = region * 8 + srow;
        __builtin_amdgcn_global_load_lds((const void*)(Kn + kbase + (size_t)row * 64 + schunk * 8),
                                         (void*)(Ks + region * 512), 16, 0, 0);
    }
#pragma unroll
    for (int rg = 0; rg < 2; rg++) {
        const int region = rg * 4 + wv;
        const int row = region * 8 + srow;
        __builtin_amdgcn_global_load_lds((const void*)(Wt + (size_t)bh * 4096 + (size_t)row * 64 + schunk * 8),
                                         (void*)(Wts + region * 512), 16, 0, 0);
    }
    __syncthreads();

    f32x4 acc[2][4] = {};
#pragma unroll
    for (int s = 0; s < 2; s++) {
        const int ch = (s * 4 + quad) ^ (l15 & 7);
        bf16x8 af[2], bfr[4];
#pragma unroll
        for (int i = 0; i < 2; i++) {
            const int row = wv * 32 + i * 16 + l15;
            af[i] = *reinterpret_cast<const bf16x8*>(&Ks[row * 64 + ch * 8]);
        }
#pragma unroll
        for (int j = 0; j < 4; j++) {
            const int d = j * 16 + l15;
            bfr[j] = *reinterpret_cast<const bf16x8*>(&Wts[d * 64 + ch * 8]);
        }
#pragma unroll
        for (int i = 0; i < 2; i++)
#pragma unroll
            for (int j = 0; j < 4; j++)
                acc[i][j] = __builtin_amdgcn_mfma_f32_16x16x32_bf16(af[i], bfr[j], acc[i][j], 0, 0, 0);
    }
    __syncthreads();

    float* Pw = Ps + wv * (32 * 68);
#pragma unroll
    for (int i = 0; i < 2; i++)
#pragma unroll
        for (int j = 0; j < 4; j++)
#pragma unroll
            for (int r = 0; r < 4; r++)
                Pw[(i * 16 + quad * 4 + r) * 68 + j * 16 + l15] = acc[i][j][r];
    __syncthreads();

#pragma unroll
    for (int rr = 0; rr < 4; rr++) {
        const int row = rr * 32 + (t >> 3);
        const float* prow = Ps + (row >> 5) * (32 * 68) + (row & 31) * 68 + sub * 8;
        const float4 p0 = *(const float4*)prow;
        const float4 p1 = *(const float4*)(prow + 4);
        uint4 rv = *(const uint4*)(Vb + kbase + (size_t)row * 64 + sub * 8);
        const HBF* hv = (const HBF*)&rv;
        const float pv[8] = {p0.x, p0.y, p0.z, p0.w, p1.x, p1.y, p1.z, p1.w};
        HBF o[8];
#pragma unroll
        for (int i = 0; i < 8; i++)
            o[i] = __float2bfloat16(fmaxf(__bfloat162float(hv[i]) + pv[i] - (STEP_C * LAMBD_C), 0.f));
        const int n = cn * 128 + row;
        *(uint4*)(AO + ((size_t)b * 2048 + n) * 768 + h * 64 + sub * 8) = *(const uint4*)o;
    }
}

// ---------------------------------------------------------------------------
extern "C" void kernel_launch(void* const* d_in, const int* in_sizes, int n_in,
                              void* d_out, int out_size, void* d_ws, size_t ws_size,
                              hipStream_t stream) {
    char* ws = (char*)d_ws;
    size_t off = 0;
    int*   flag   = (int*)(ws + off);   off += 16;
    HBF*   xb     = (HBF*)(ws + off);   off += (size_t)4096 * 768 * 2;
    HBF*   Wqkvb  = (HBF*)(ws + off);   off += (size_t)2304 * 768 * 2;
    HBF*   Wprojb = (HBF*)(ws + off);   off += (size_t)768 * 768 * 2;
    HBF*   bprojb = (HBF*)(ws + off);   off += 2048;
    HBF*   Kn     = (HBF*)(ws + off);   off += (size_t)24 * 2048 * 64 * 2;
    HBF*   Vb     = (HBF*)(ws + off);   off += (size_t)24 * 2048 * 64 * 2;
    HBF*   QKVt   = (HBF*)(ws + off);   off += (size_t)3 * 24 * 64 * 2048 * 2;
    float* P      = (float*)(ws + off); off += (size_t)24 * 8 * 12288 * 4;
    float* M      = (float*)(ws + off); off += (size_t)24 * 12288 * 4;
    HBF*   Wt     = (HBF*)(ws + off);   off += (size_t)24 * 4096 * 2;
    HBF*   AO     = (HBF*)(ws + off);   off += (size_t)4096 * 768 * 2;
    // total ~60 MB

    // 0) dtype detect (+ convert only if fp32 inputs)
    convert_all<<<256, 256, 0, stream>>>(d_in[0], d_in[1], d_in[2], d_in[3],
                                         xb, Wqkvb, Wprojb, bprojb, flag);

    // 1) qkv GEMM (double-buffered, 64x128 tiles, 1152 blocks — R9 optimum):
    //    fused L2-norm + head-split natural (Kn, V) + transposed (QKVt)
    gemm_db<64, 128, false, false, true><<<dim3(64, 18), 256, 0, stream>>>(
        xb, d_in[0], Wqkvb, d_in[1], nullptr, nullptr,
        nullptr, Kn, Vb, QKVt, 4096, 2304, 768, flag);

    // 2) MFMA Gram partials (8 slabs) + full-BW tree reduce
    gram_mfma<<<dim3(24, 8), 256, 0, stream>>>(QKVt, P);
    gram_reduce<<<1152, 256, 0, stream>>>(P, M);

    // 3) W combine -> transposed bf16 Wt (192 blocks)
    combine_w<<<dim3(24, 8), 256, 0, stream>>>(M, Wt);

    // 4) MFMA epilogue: relu(V + Kn@W - 0.05) -> [B,N,C] bf16
    epilogue_attn<<<dim3(24, 16), 256, 0, stream>>>(Kn, Vb, Wt, AO);

    // 5) out = AO @ Wproj^T + bproj (double-buffered, 64x64 tiles, 768 blocks)
    gemm_db<64, 64, true, true, false><<<dim3(64, 12), 256, 0, stream>>>(
        AO, AO, Wprojb, d_in[2], bprojb, d_in[3],
        d_out, nullptr, nullptr, nullptr, 4096, 768, 768, flag);
}